// Round 3
// baseline (821.150 us; speedup 1.0000x reference)
//
#include <hip/hip_runtime.h>
#include <math.h>

#define D_MODEL 1024
#define NHEAD   16
#define DH      64
#define BATCH   4
#define SEQ     1024
#define TKV     576
#define MQ      (BATCH * SEQ)   // 4096
#define MKV     (BATCH * TKV)   // 2304

typedef __attribute__((ext_vector_type(8))) short bf16x8;
typedef __attribute__((ext_vector_type(4))) float f32x4;

// ---------------------------------------------------------------------------
// bf16 helpers (bit-level, RNE)
// ---------------------------------------------------------------------------
__device__ __forceinline__ unsigned short f2bf(float x) {
    unsigned int u = __float_as_uint(x);
    unsigned int r = (u + 0x7FFFu + ((u >> 16) & 1u)) >> 16;
    return (unsigned short)r;
}
__device__ __forceinline__ float bf2f(unsigned short b) {
    return __uint_as_float((unsigned int)b << 16);
}
__device__ __forceinline__ void split2(float x, unsigned short& h, unsigned short& l) {
    h = f2bf(x);
    l = f2bf(x - bf2f(h));   // residual ~2^-17 rel after both terms
}

// async global->LDS 16B copy; LDS dest = wave-uniform base + lane*16
__device__ __forceinline__ void async_copy16(const void* g, void* l) {
    auto gp = (const __attribute__((address_space(1))) unsigned int*)(g);
    auto lp = (__attribute__((address_space(3))) unsigned int*)(l);
    __builtin_amdgcn_global_load_lds(gp, lp, 16, 0, 0);
}

// ---------------------------------------------------------------------------
// split_rm: fp32 [M][K] row-major -> bf16 hi/lo [M][K]. One float4 per thread.
// ---------------------------------------------------------------------------
__global__ __launch_bounds__(256) void split_rm(
    const float* __restrict__ in,
    unsigned short* __restrict__ oh, unsigned short* __restrict__ ol)
{
    const size_t i = (size_t)blockIdx.x * 256 + threadIdx.x;
    const float4 v = reinterpret_cast<const float4*>(in)[i];
    ushort4 h, l;
    split2(v.x, h.x, l.x);
    split2(v.y, h.y, l.y);
    split2(v.z, h.z, l.z);
    split2(v.w, h.w, l.w);
    reinterpret_cast<ushort4*>(oh)[i] = h;
    reinterpret_cast<ushort4*>(ol)[i] = l;
}

// ---------------------------------------------------------------------------
// split_tr: W fp32 [K][N] (leading dim ld) -> Bt hi/lo bf16 [N][K=1024].
// 32x32 tile via padded LDS transpose.
// ---------------------------------------------------------------------------
__global__ __launch_bounds__(256) void split_tr(
    const float* __restrict__ W, int ld,
    unsigned short* __restrict__ th, unsigned short* __restrict__ tl)
{
    __shared__ float sh[32][33];
    const int k0 = blockIdx.x * 32;
    const int n0 = blockIdx.y * 32;
    const int t  = threadIdx.x;
    const int r  = t >> 3;
    const int c4 = (t & 7) * 4;

    const float4 v = *reinterpret_cast<const float4*>(&W[(size_t)(k0 + r) * ld + n0 + c4]);
    sh[r][c4 + 0] = v.x;
    sh[r][c4 + 1] = v.y;
    sh[r][c4 + 2] = v.z;
    sh[r][c4 + 3] = v.w;
    __syncthreads();

    ushort4 h, l;
    split2(sh[c4 + 0][r], h.x, l.x);
    split2(sh[c4 + 1][r], h.y, l.y);
    split2(sh[c4 + 2][r], h.z, l.z);
    split2(sh[c4 + 3][r], h.w, l.w);
    *reinterpret_cast<ushort4*>(&th[(size_t)(n0 + r) * 1024 + k0 + c4]) = h;
    *reinterpret_cast<ushort4*>(&tl[(size_t)(n0 + r) * 1024 + k0 + c4]) = l;
}

// ---------------------------------------------------------------------------
// Split-bf16 MFMA GEMM: C[M][1024] = A[M][1024] @ B[1024][1024] + bias.
// A as hi/lo bf16 row-major [M][K]; B TRANSPOSED as hi/lo [N][K].
// acc += Ah*Bh + Ah*Bl + Al*Bh  (Al*Bl ~2^-18, dropped).
// Tile 128x128, BK=32, 256 thr = 4 waves, wave = 4x4 frags of 16x16x32.
// LDS tiles [128][32] bf16 LINEAR: 64B row stride means the frag-read pattern
// (lane&15 rows x (lane>>4)*16B chunks) already spreads 8 dwords/bank —
// structurally conflict-free for ds_read_b128; no swizzle needed.
// ---------------------------------------------------------------------------
__global__ __launch_bounds__(256) void gemm_split_mfma(
    const unsigned short* __restrict__ Ah, const unsigned short* __restrict__ Al,
    const unsigned short* __restrict__ Bth, const unsigned short* __restrict__ Btl,
    const float* __restrict__ bias,
    float* __restrict__ C, int M)
{
    __shared__ unsigned short lds[4 * 4096];   // Ah | Al | Bh | Bl, 8KB each
    const unsigned short* lAh = lds;
    const unsigned short* lAl = lds + 4096;
    const unsigned short* lBh = lds + 8192;
    const unsigned short* lBl = lds + 12288;

    const int tid  = threadIdx.x;
    const int lane = tid & 63;
    const int wv   = tid >> 6;

    // XCD-aware chunked block swizzle (gridDim.x == 8 always; nwg % 8 == 0)
    const int nwg = (gridDim.y << 3);
    const int lin = blockIdx.y * 8 + blockIdx.x;
    const int cpx = nwg >> 3;
    const int swz = (lin & 7) * cpx + (lin >> 3);
    const int brow = (swz >> 3) * 128;
    const int bcol = (swz & 7) * 128;

    const int wr = (wv >> 1) * 64;   // wave row offset in tile
    const int wc = (wv & 1) * 64;    // wave col offset in tile
    const int lr = lane & 15;
    const int kg = lane >> 4;        // k-chunk group 0..3

    f32x4 acc[4][4];
#pragma unroll
    for (int i = 0; i < 4; ++i)
#pragma unroll
        for (int j = 0; j < 4; ++j) acc[i][j] = (f32x4){0.f, 0.f, 0.f, 0.f};

    for (int k0 = 0; k0 < 1024; k0 += 32) {
        // ---- stage 4 tiles of [128][32] bf16; 512 16B-chunks each, linear ----
#pragma unroll
        for (int i = 0; i < 2; ++i) {
            const int ci = i * 256 + tid;          // chunk index 0..511
            const int r  = ci >> 2;                // tile row 0..127
            const int c  = ci & 3;                 // 16B chunk within row
            const size_t aoff = (size_t)(brow + r) * 1024 + k0 + c * 8;
            const size_t boff = (size_t)(bcol + r) * 1024 + k0 + c * 8;
            char* ldst = (char*)lds + i * 4096 + wv * 1024;   // wave-uniform base
            async_copy16(Ah  + aoff, ldst);
            async_copy16(Al  + aoff, ldst + 8192);
            async_copy16(Bth + boff, ldst + 16384);
            async_copy16(Btl + boff, ldst + 24576);
        }
        __syncthreads();

        // ---- fragment loads (linear ds_read_b128) ----
        bf16x8 afh[4], afl[4], bfh[4], bfl[4];
#pragma unroll
        for (int f = 0; f < 4; ++f) {
            const int mb = (wr + f * 16 + lr) * 64 + kg * 16;   // byte offset
            const int nb = (wc + f * 16 + lr) * 64 + kg * 16;
            afh[f] = *(const bf16x8*)((const char*)lAh + mb);
            afl[f] = *(const bf16x8*)((const char*)lAl + mb);
            bfh[f] = *(const bf16x8*)((const char*)lBh + nb);
            bfl[f] = *(const bf16x8*)((const char*)lBl + nb);
        }

        // ---- 48 MFMA ----
#pragma unroll
        for (int mf = 0; mf < 4; ++mf)
#pragma unroll
            for (int nf = 0; nf < 4; ++nf) {
                acc[mf][nf] = __builtin_amdgcn_mfma_f32_16x16x32_bf16(afh[mf], bfh[nf], acc[mf][nf], 0, 0, 0);
                acc[mf][nf] = __builtin_amdgcn_mfma_f32_16x16x32_bf16(afh[mf], bfl[nf], acc[mf][nf], 0, 0, 0);
                acc[mf][nf] = __builtin_amdgcn_mfma_f32_16x16x32_bf16(afl[mf], bfh[nf], acc[mf][nf], 0, 0, 0);
            }
        __syncthreads();
    }

    // ---- epilogue: bias + store. D: col=lane&15, row=(lane>>4)*4+reg ----
#pragma unroll
    for (int mf = 0; mf < 4; ++mf)
#pragma unroll
        for (int nf = 0; nf < 4; ++nf)
#pragma unroll
            for (int j = 0; j < 4; ++j) {
                const int row = brow + wr + mf * 16 + kg * 4 + j;
                const int col = bcol + wc + nf * 16 + lr;
                C[(size_t)row * 1024 + col] = acc[mf][nf][j] + bias[col];
            }
}

// ---------------------------------------------------------------------------
// Flash-style cross-attention (fp32 VALU), emits bf16 hi/lo for final GEMM.
// q: [B*S][1024] fp32, kv: [B*T][1024] fp32 (same buffer used as K and V).
// Block: 256 thr = 4 waves; 32 q-rows per block (8/wave). Grid (S/32, B*H).
// ---------------------------------------------------------------------------
__global__ __launch_bounds__(256) void attn_kernel(
    const float* __restrict__ q,
    const float* __restrict__ kv,
    unsigned short* __restrict__ ah, unsigned short* __restrict__ al)
{
    // kv pad 65: score read kv[lane][d] banks (lane+d)%32 -> 2-way (free);
    //            PV read kv[t][lane] banks (t+lane)%32 -> 2-way (free).
    __shared__ float kv_lds[64][65];
    __shared__ float q_lds[32][68];

    const int tid  = threadIdx.x;
    const int lane = tid & 63;
    const int wave = tid >> 6;
    const int s0   = blockIdx.x * 32;
    const int bh   = blockIdx.y;
    const int b    = bh >> 4;
    const int h    = bh & 15;

    // stage q tile: 32 rows x 64 floats = 512 float4, 2 per thread
#pragma unroll
    for (int it = 0; it < 2; ++it) {
        const int idx = it * 256 + tid;
        const int r   = idx >> 4;
        const int d4  = (idx & 15) * 4;
        const float4 v = *reinterpret_cast<const float4*>(
            &q[(size_t)(b * SEQ + s0 + r) * D_MODEL + h * DH + d4]);
        *reinterpret_cast<float4*>(&q_lds[r][d4]) = v;
    }
    // (first __syncthreads below covers q_lds visibility)

    float m[8], l[8], o[8], pcur[8];
#pragma unroll
    for (int r = 0; r < 8; ++r) { m[r] = -INFINITY; l[r] = 0.f; o[r] = 0.f; }

    const int rq = wave * 8;

    for (int tile = 0; tile < TKV / 64; ++tile) {
        // ---- stage kv tile: 64 rows x 64 floats ----
#pragma unroll
        for (int it = 0; it < 4; ++it) {
            const int idx = tid + it * 256;
            const int row = idx >> 4;
            const int d4  = (idx & 15) * 4;
            const float4 v = *reinterpret_cast<const float4*>(
                &kv[(size_t)(b * TKV + tile * 64 + row) * D_MODEL + h * DH + d4]);
            kv_lds[row][d4 + 0] = v.x;
            kv_lds[row][d4 + 1] = v.y;
            kv_lds[row][d4 + 2] = v.z;
            kv_lds[row][d4 + 3] = v.w;
        }
        __syncthreads();

        // ---- scores: lane owns kv row t = lane; 8 q-rows per lane ----
        float s4[8] = {0.f, 0.f, 0.f, 0.f, 0.f, 0.f, 0.f, 0.f};
#pragma unroll
        for (int d4 = 0; d4 < DH; d4 += 4) {
            const float k0v = kv_lds[lane][d4 + 0];
            const float k1v = kv_lds[lane][d4 + 1];
            const float k2v = kv_lds[lane][d4 + 2];
            const float k3v = kv_lds[lane][d4 + 3];
#pragma unroll
            for (int r = 0; r < 8; ++r) {
                const float4 qv = *reinterpret_cast<const float4*>(&q_lds[rq + r][d4]);
                s4[r] = fmaf(qv.x, k0v, s4[r]);
                s4[r] = fmaf(qv.y, k1v, s4[r]);
                s4[r] = fmaf(qv.z, k2v, s4[r]);
                s4[r] = fmaf(qv.w, k3v, s4[r]);
            }
        }

        // ---- online softmax per row ----
#pragma unroll
        for (int r = 0; r < 8; ++r) {
            const float s = s4[r] * 0.125f;   // 1/sqrt(64)
            float mx = s;
#pragma unroll
            for (int off = 32; off; off >>= 1) mx = fmaxf(mx, __shfl_xor(mx, off));
            const float mnew = fmaxf(m[r], mx);
            const float p = __expf(s - mnew);
            float ps = p;
#pragma unroll
            for (int off = 32; off; off >>= 1) ps += __shfl_xor(ps, off);
            const float corr = __expf(m[r] - mnew);   // exp(-inf)=0 on first tile
            l[r] = l[r] * corr + ps;
            o[r] *= corr;
            m[r] = mnew;
            pcur[r] = p;
        }

        // ---- PV: o[d=lane] += sum_t p[t] * kv[t][lane] ----
#pragma unroll
        for (int t = 0; t < 64; ++t) {
            const float kvv = kv_lds[t][lane];
#pragma unroll
            for (int r = 0; r < 8; ++r) {
                const float w = __shfl(pcur[r], t);   // uniform t -> readlane
                o[r] = fmaf(w, kvv, o[r]);
            }
        }
        __syncthreads();
    }

#pragma unroll
    for (int r = 0; r < 8; ++r) {
        const float res = o[r] / l[r];
        const size_t idx = (size_t)(b * SEQ + s0 + rq + r) * D_MODEL + h * DH + lane;
        unsigned short hh, ll;
        split2(res, hh, ll);
        ah[idx] = hh;
        al[idx] = ll;
    }
}

// ---------------------------------------------------------------------------
extern "C" void kernel_launch(void* const* d_in, const int* in_sizes, int n_in,
                              void* d_out, int out_size, void* d_ws, size_t ws_size,
                              hipStream_t stream)
{
    const float* x      = (const float*)d_in[0];
    const float* enc    = (const float*)d_in[1];
    const float* w_attn = (const float*)d_in[2];
    const float* b_attn = (const float*)d_in[3];
    const float* w_vis  = (const float*)d_in[4];
    const float* b_vis  = (const float*)d_in[5];
    const float* w_proj = (const float*)d_in[6];
    const float* b_proj = (const float*)d_in[7];
    float* out = (float*)d_out;

    // ---- workspace carve-up (~62.6 MB; att h/l aliases xh/xl, dead after GEMM1)
    char* p = (char*)d_ws;
    unsigned short* xh   = (unsigned short*)p; p += (size_t)MQ  * 1024 * 2;
    unsigned short* xl   = (unsigned short*)p; p += (size_t)MQ  * 1024 * 2;
    unsigned short* ench = (unsigned short*)p; p += (size_t)MKV * 1024 * 2;
    unsigned short* encl = (unsigned short*)p; p += (size_t)MKV * 1024 * 2;
    unsigned short* w1h  = (unsigned short*)p; p += (size_t)1024 * 1024 * 2;
    unsigned short* w1l  = (unsigned short*)p; p += (size_t)1024 * 1024 * 2;
    unsigned short* w2h  = (unsigned short*)p; p += (size_t)1024 * 1024 * 2;
    unsigned short* w2l  = (unsigned short*)p; p += (size_t)1024 * 1024 * 2;
    unsigned short* w3h  = (unsigned short*)p; p += (size_t)1024 * 1024 * 2;
    unsigned short* w3l  = (unsigned short*)p; p += (size_t)1024 * 1024 * 2;
    float* q  = (float*)p; p += (size_t)MQ  * 1024 * 4;
    float* kv = (float*)p; p += (size_t)MKV * 1024 * 4;
    unsigned short* atth = xh;   // reuse (xh/xl dead after GEMM1)
    unsigned short* attl = xl;

    // ---- operand prep ----
    split_rm<<<(MQ  * 1024 / 4) / 256, 256, 0, stream>>>(x, xh, xl);
    split_rm<<<(MKV * 1024 / 4) / 256, 256, 0, stream>>>(enc, ench, encl);
    split_tr<<<dim3(32, 32), 256, 0, stream>>>(w_attn, 3 * D_MODEL, w1h, w1l); // q-slice
    split_tr<<<dim3(32, 32), 256, 0, stream>>>(w_vis,  D_MODEL, w2h, w2l);
    split_tr<<<dim3(32, 32), 256, 0, stream>>>(w_proj, D_MODEL, w3h, w3l);

    // ---- q = x @ w_attn[:, :D] + b_attn[:D] ----
    gemm_split_mfma<<<dim3(8, MQ / 128), 256, 0, stream>>>(xh, xl, w1h, w1l, b_attn, q, MQ);
    // ---- kv = enc @ w_vis + b_vis ----
    gemm_split_mfma<<<dim3(8, MKV / 128), 256, 0, stream>>>(ench, encl, w2h, w2l, b_vis, kv, MKV);
    // ---- attention -> bf16 hi/lo ----
    attn_kernel<<<dim3(SEQ / 32, BATCH * NHEAD), 256, 0, stream>>>(q, kv, atth, attl);
    // ---- out = att @ w_proj + b_proj ----
    gemm_split_mfma<<<dim3(8, MQ / 128), 256, 0, stream>>>(atth, attl, w3h, w3l, b_proj, out, MQ);
}

// Round 4
// 312.485 us; speedup vs baseline: 2.6278x; 2.6278x over previous
//
#include <hip/hip_runtime.h>
#include <math.h>

#define D_MODEL 1024
#define NHEAD   16
#define DH      64
#define BATCH   4
#define SEQ     1024
#define TKV     576
#define MQ      (BATCH * SEQ)   // 4096
#define MKV     (BATCH * TKV)   // 2304

typedef __attribute__((ext_vector_type(8))) short bf16x8;
typedef __attribute__((ext_vector_type(4))) float f32x4;
typedef unsigned short ushort_t;

// ---------------------------------------------------------------------------
// bf16 helpers (bit-level, RNE)
// ---------------------------------------------------------------------------
__device__ __forceinline__ unsigned short f2bf(float x) {
    unsigned int u = __float_as_uint(x);
    unsigned int r = (u + 0x7FFFu + ((u >> 16) & 1u)) >> 16;
    return (unsigned short)r;
}
__device__ __forceinline__ float bf2f(unsigned short b) {
    return __uint_as_float((unsigned int)b << 16);
}
__device__ __forceinline__ void split2(float x, unsigned short& h, unsigned short& l) {
    h = f2bf(x);
    l = f2bf(x - bf2f(h));   // residual ~2^-17 rel
}

// async global->LDS 16B copy; LDS dest = wave-uniform base + lane*16
__device__ __forceinline__ void async_copy16(const void* g, void* l) {
    auto gp = (const __attribute__((address_space(1))) unsigned int*)(g);
    auto lp = (__attribute__((address_space(3))) unsigned int*)(l);
    __builtin_amdgcn_global_load_lds(gp, lp, 16, 0, 0);
}

// ---------------------------------------------------------------------------
// split_rm: fp32 [M][K] row-major -> bf16 hi/lo [M][K]. One float4 per thread.
// ---------------------------------------------------------------------------
__global__ __launch_bounds__(256) void split_rm(
    const float* __restrict__ in,
    unsigned short* __restrict__ oh, unsigned short* __restrict__ ol)
{
    const size_t i = (size_t)blockIdx.x * 256 + threadIdx.x;
    const float4 v = reinterpret_cast<const float4*>(in)[i];
    ushort4 h, l;
    split2(v.x, h.x, l.x);
    split2(v.y, h.y, l.y);
    split2(v.z, h.z, l.z);
    split2(v.w, h.w, l.w);
    reinterpret_cast<ushort4*>(oh)[i] = h;
    reinterpret_cast<ushort4*>(ol)[i] = l;
}

// ---------------------------------------------------------------------------
// split_tr: W fp32 [K][N] (leading dim ld) -> Bt hi/lo bf16 [N][K=1024].
// ---------------------------------------------------------------------------
__global__ __launch_bounds__(256) void split_tr(
    const float* __restrict__ W, int ld,
    unsigned short* __restrict__ th, unsigned short* __restrict__ tl)
{
    __shared__ float sh[32][33];
    const int k0 = blockIdx.x * 32;
    const int n0 = blockIdx.y * 32;
    const int t  = threadIdx.x;
    const int r  = t >> 3;
    const int c4 = (t & 7) * 4;

    const float4 v = *reinterpret_cast<const float4*>(&W[(size_t)(k0 + r) * ld + n0 + c4]);
    sh[r][c4 + 0] = v.x;
    sh[r][c4 + 1] = v.y;
    sh[r][c4 + 2] = v.z;
    sh[r][c4 + 3] = v.w;
    __syncthreads();

    ushort4 h, l;
    split2(sh[c4 + 0][r], h.x, l.x);
    split2(sh[c4 + 1][r], h.y, l.y);
    split2(sh[c4 + 2][r], h.z, l.z);
    split2(sh[c4 + 3][r], h.w, l.w);
    *reinterpret_cast<ushort4*>(&th[(size_t)(n0 + r) * 1024 + k0 + c4]) = h;
    *reinterpret_cast<ushort4*>(&tl[(size_t)(n0 + r) * 1024 + k0 + c4]) = l;
}

// ---------------------------------------------------------------------------
// transpose_hl: kvh/kvl [B*T][1024] -> kvT [bh][64 d][576 t] (both hi & lo).
// Per block: one 64t x 64d tile of one (b,h). Scalar transposed LDS writes,
// vector b128 reads + coalesced 16B global stores.
// ---------------------------------------------------------------------------
__global__ __launch_bounds__(256) void transpose_hl(
    const unsigned short* __restrict__ kvh, const unsigned short* __restrict__ kvl,
    unsigned short* __restrict__ kvth, unsigned short* __restrict__ kvtl)
{
    __shared__ __align__(16) unsigned short th_[64][72];   // [d][t]
    __shared__ __align__(16) unsigned short tl_[64][72];
    const int tid = threadIdx.x;
    const int t0  = blockIdx.x * 64;
    const int bh  = blockIdx.y;
    const int b   = bh >> 4;
    const int h   = bh & 15;

#pragma unroll
    for (int p = 0; p < 2; ++p) {
        const int idx = p * 256 + tid;
        const int rr  = idx >> 3;   // t within tile
        const int c   = idx & 7;    // 8-ushort chunk along d
        const size_t src = (size_t)(b * TKV + t0 + rr) * 1024 + h * DH + c * 8;
        const bf16x8 vh = *(const bf16x8*)&kvh[src];
        const bf16x8 vl = *(const bf16x8*)&kvl[src];
#pragma unroll
        for (int e = 0; e < 8; ++e) {
            th_[c * 8 + e][rr] = (unsigned short)vh[e];
            tl_[c * 8 + e][rr] = (unsigned short)vl[e];
        }
    }
    __syncthreads();

#pragma unroll
    for (int p = 0; p < 2; ++p) {
        const int idx = p * 256 + tid;
        const int d   = idx >> 3;
        const int c2  = idx & 7;
        const size_t dst = (size_t)(bh * 64 + d) * TKV + t0 + c2 * 8;
        *(bf16x8*)&kvth[dst] = *(const bf16x8*)&th_[d][c2 * 8];
        *(bf16x8*)&kvtl[dst] = *(const bf16x8*)&tl_[d][c2 * 8];
    }
}

// ---------------------------------------------------------------------------
// Split-bf16 MFMA GEMM (validated round 3). BF16OUT=false: fp32 C + bias.
// BF16OUT=true: writes split2(acc+bias) into Ch/Cl instead.
// ---------------------------------------------------------------------------
template<bool BF16OUT>
__global__ __launch_bounds__(256) void gemm_split_mfma(
    const unsigned short* __restrict__ Ah, const unsigned short* __restrict__ Al,
    const unsigned short* __restrict__ Bth, const unsigned short* __restrict__ Btl,
    const float* __restrict__ bias,
    float* __restrict__ C,
    unsigned short* __restrict__ Ch, unsigned short* __restrict__ Cl,
    int M)
{
    __shared__ unsigned short lds[4 * 4096];   // Ah | Al | Bh | Bl, 8KB each
    const unsigned short* lAh = lds;
    const unsigned short* lAl = lds + 4096;
    const unsigned short* lBh = lds + 8192;
    const unsigned short* lBl = lds + 12288;

    const int tid  = threadIdx.x;
    const int lane = tid & 63;
    const int wv   = tid >> 6;

    // XCD-aware chunked block swizzle (gridDim.x == 8; nwg % 8 == 0)
    const int nwg = (gridDim.y << 3);
    const int lin = blockIdx.y * 8 + blockIdx.x;
    const int cpx = nwg >> 3;
    const int swz = (lin & 7) * cpx + (lin >> 3);
    const int brow = (swz >> 3) * 128;
    const int bcol = (swz & 7) * 128;

    const int wr = (wv >> 1) * 64;
    const int wc = (wv & 1) * 64;
    const int lr = lane & 15;
    const int kg = lane >> 4;

    f32x4 acc[4][4];
#pragma unroll
    for (int i = 0; i < 4; ++i)
#pragma unroll
        for (int j = 0; j < 4; ++j) acc[i][j] = (f32x4){0.f, 0.f, 0.f, 0.f};

    for (int k0 = 0; k0 < 1024; k0 += 32) {
#pragma unroll
        for (int i = 0; i < 2; ++i) {
            const int ci = i * 256 + tid;
            const int r  = ci >> 2;
            const int c  = ci & 3;
            const size_t aoff = (size_t)(brow + r) * 1024 + k0 + c * 8;
            const size_t boff = (size_t)(bcol + r) * 1024 + k0 + c * 8;
            char* ldst = (char*)lds + i * 4096 + wv * 1024;
            async_copy16(Ah  + aoff, ldst);
            async_copy16(Al  + aoff, ldst + 8192);
            async_copy16(Bth + boff, ldst + 16384);
            async_copy16(Btl + boff, ldst + 24576);
        }
        __syncthreads();

        bf16x8 afh[4], afl[4], bfh[4], bfl[4];
#pragma unroll
        for (int f = 0; f < 4; ++f) {
            const int mb = (wr + f * 16 + lr) * 64 + kg * 16;
            const int nb = (wc + f * 16 + lr) * 64 + kg * 16;
            afh[f] = *(const bf16x8*)((const char*)lAh + mb);
            afl[f] = *(const bf16x8*)((const char*)lAl + mb);
            bfh[f] = *(const bf16x8*)((const char*)lBh + nb);
            bfl[f] = *(const bf16x8*)((const char*)lBl + nb);
        }

#pragma unroll
        for (int mf = 0; mf < 4; ++mf)
#pragma unroll
            for (int nf = 0; nf < 4; ++nf) {
                acc[mf][nf] = __builtin_amdgcn_mfma_f32_16x16x32_bf16(afh[mf], bfh[nf], acc[mf][nf], 0, 0, 0);
                acc[mf][nf] = __builtin_amdgcn_mfma_f32_16x16x32_bf16(afh[mf], bfl[nf], acc[mf][nf], 0, 0, 0);
                acc[mf][nf] = __builtin_amdgcn_mfma_f32_16x16x32_bf16(afl[mf], bfh[nf], acc[mf][nf], 0, 0, 0);
            }
        __syncthreads();
    }

    // epilogue. D: col=lane&15, row=(lane>>4)*4+reg (validated)
#pragma unroll
    for (int mf = 0; mf < 4; ++mf)
#pragma unroll
        for (int nf = 0; nf < 4; ++nf)
#pragma unroll
            for (int j = 0; j < 4; ++j) {
                const int row = brow + wr + mf * 16 + kg * 4 + j;
                const int col = bcol + wc + nf * 16 + lr;
                const float v = acc[mf][nf][j] + bias[col];
                if constexpr (BF16OUT) {
                    unsigned short hh, ll;
                    split2(v, hh, ll);
                    Ch[(size_t)row * 1024 + col] = hh;
                    Cl[(size_t)row * 1024 + col] = ll;
                } else {
                    C[(size_t)row * 1024 + col] = v;
                }
            }
}

// ---------------------------------------------------------------------------
// MFMA flash cross-attention.
// qh/ql: [MQ][1024] bf16 hi/lo. kvh/kvl: [MKV][1024]. kvth/kvtl: [bh][64][576].
// Output ah/al: [MQ][1024] bf16 hi/lo.
// Block 256 = 4 waves; wave owns 16 q-rows; QBLK=64/block. KV tiles of 64.
// Grid (SEQ/64=16, B*H=64).
// QK^T: A=Q-frag (validated GEMM A pattern), B=KV rows (validated Bt pattern).
// PV:   A=P (LDS round-trip), B=KV^T rows (Bt pattern).
// All products 3-term hi/lo split.
// ---------------------------------------------------------------------------
__global__ __launch_bounds__(256) void attn_mfma(
    const unsigned short* __restrict__ qh, const unsigned short* __restrict__ ql,
    const unsigned short* __restrict__ kvh, const unsigned short* __restrict__ kvl,
    const unsigned short* __restrict__ kvth, const unsigned short* __restrict__ kvtl,
    unsigned short* __restrict__ ah, unsigned short* __restrict__ al)
{
    // 72-ushort rows (144B = 36 dw, %32=4) -> frag reads rotate 4 banks/row:
    // 64 lanes spread uniformly 8/bank = structural minimum, conflict-free.
    __shared__ __align__(16) unsigned short kh_s[64][72], kl_s[64][72];
    __shared__ __align__(16) unsigned short vth_s[64][72], vtl_s[64][72];
    // P per wave: 80-ushort rows (160B = 40 dw, %32=8) -> conflict-free for
    // both the scalar C-layout writes and the b128 A-frag reads.
    __shared__ __align__(16) unsigned short ph_s[4][16][80], pl_s[4][16][80];

    const int tid  = threadIdx.x;
    const int lane = tid & 63;
    const int w    = tid >> 6;
    const int lr   = lane & 15;
    const int kg   = lane >> 4;
    const int s0   = blockIdx.x * 64;
    const int bh   = blockIdx.y;
    const int b    = bh >> 4;
    const int h    = bh & 15;

    // ---- Q fragments, hoisted (per-wave 16 rows) ----
    bf16x8 qhf[2], qlf[2];
    {
        const size_t qoff = (size_t)(b * SEQ + s0 + w * 16 + lr) * 1024 + h * DH;
#pragma unroll
        for (int c = 0; c < 2; ++c) {
            qhf[c] = *(const bf16x8*)&qh[qoff + c * 32 + kg * 8];
            qlf[c] = *(const bf16x8*)&ql[qoff + c * 32 + kg * 8];
        }
    }

    f32x4 oacc[4];
#pragma unroll
    for (int nf = 0; nf < 4; ++nf) oacc[nf] = (f32x4){0.f, 0.f, 0.f, 0.f};
    float m_r[4], l_r[4];
#pragma unroll
    for (int j = 0; j < 4; ++j) { m_r[j] = -INFINITY; l_r[j] = 0.f; }

    for (int it = 0; it < TKV / 64; ++it) {
        const int t0 = it * 64;

        // ---- stage KV row-major + KV^T tiles (bf16x8 load -> ds_write_b128)
#pragma unroll
        for (int i = 0; i < 2; ++i) {
            const int idx = i * 256 + tid;
            const int r   = idx >> 3;
            const int c   = idx & 7;
            const size_t kvo = (size_t)(b * TKV + t0 + r) * 1024 + h * DH + c * 8;
            const size_t vto = (size_t)(bh * 64 + r) * TKV + t0 + c * 8;
            *(bf16x8*)&kh_s[r][c * 8]  = *(const bf16x8*)&kvh[kvo];
            *(bf16x8*)&kl_s[r][c * 8]  = *(const bf16x8*)&kvl[kvo];
            *(bf16x8*)&vth_s[r][c * 8] = *(const bf16x8*)&kvth[vto];
            *(bf16x8*)&vtl_s[r][c * 8] = *(const bf16x8*)&kvtl[vto];
        }
        __syncthreads();

        // ---- QK^T: S[16 s][64 t], 3-term split ----
        f32x4 sacc[4];
#pragma unroll
        for (int nf = 0; nf < 4; ++nf) sacc[nf] = (f32x4){0.f, 0.f, 0.f, 0.f};
#pragma unroll
        for (int c = 0; c < 2; ++c)
#pragma unroll
            for (int nf = 0; nf < 4; ++nf) {
                const bf16x8 bhf = *(const bf16x8*)&kh_s[nf * 16 + lr][c * 32 + kg * 8];
                const bf16x8 blf = *(const bf16x8*)&kl_s[nf * 16 + lr][c * 32 + kg * 8];
                sacc[nf] = __builtin_amdgcn_mfma_f32_16x16x32_bf16(qhf[c], bhf, sacc[nf], 0, 0, 0);
                sacc[nf] = __builtin_amdgcn_mfma_f32_16x16x32_bf16(qhf[c], blf, sacc[nf], 0, 0, 0);
                sacc[nf] = __builtin_amdgcn_mfma_f32_16x16x32_bf16(qlf[c], bhf, sacc[nf], 0, 0, 0);
            }

        // ---- online softmax in C-layout (row s = kg*4+j, col t = nf*16+lr)
#pragma unroll
        for (int j = 0; j < 4; ++j) {
            float s0v = sacc[0][j] * 0.125f;
            float s1v = sacc[1][j] * 0.125f;
            float s2v = sacc[2][j] * 0.125f;
            float s3v = sacc[3][j] * 0.125f;
            float mx = fmaxf(fmaxf(s0v, s1v), fmaxf(s2v, s3v));
            mx = fmaxf(mx, __shfl_xor(mx, 1));
            mx = fmaxf(mx, __shfl_xor(mx, 2));
            mx = fmaxf(mx, __shfl_xor(mx, 4));
            mx = fmaxf(mx, __shfl_xor(mx, 8));
            const float mnew = fmaxf(m_r[j], mx);
            const float corr = __expf(m_r[j] - mnew);   // 0 on first tile
            const float p0 = __expf(s0v - mnew);
            const float p1 = __expf(s1v - mnew);
            const float p2 = __expf(s2v - mnew);
            const float p3 = __expf(s3v - mnew);
            float ps = p0 + p1 + p2 + p3;
            ps += __shfl_xor(ps, 1);
            ps += __shfl_xor(ps, 2);
            ps += __shfl_xor(ps, 4);
            ps += __shfl_xor(ps, 8);
            l_r[j] = l_r[j] * corr + ps;
            m_r[j] = mnew;
#pragma unroll
            for (int nf = 0; nf < 4; ++nf) oacc[nf][j] *= corr;
            // store P (hi/lo) to per-wave LDS tile, C-layout positions
            const int srow = kg * 4 + j;
            unsigned short hh, ll;
            split2(p0, hh, ll); ph_s[w][srow][ 0 + lr] = hh; pl_s[w][srow][ 0 + lr] = ll;
            split2(p1, hh, ll); ph_s[w][srow][16 + lr] = hh; pl_s[w][srow][16 + lr] = ll;
            split2(p2, hh, ll); ph_s[w][srow][32 + lr] = hh; pl_s[w][srow][32 + lr] = ll;
            split2(p3, hh, ll); ph_s[w][srow][48 + lr] = hh; pl_s[w][srow][48 + lr] = ll;
        }

        // ---- PV: O[16 s][64 d] += P[16 s][64 t] @ V[64 t][64 d] ----
        // (P is wave-local: same-wave DS ordering makes writes visible; no barrier)
#pragma unroll
        for (int c = 0; c < 2; ++c) {
            const bf16x8 pha = *(const bf16x8*)&ph_s[w][lr][c * 32 + kg * 8];
            const bf16x8 pla = *(const bf16x8*)&pl_s[w][lr][c * 32 + kg * 8];
#pragma unroll
            for (int nf = 0; nf < 4; ++nf) {
                const bf16x8 vhf = *(const bf16x8*)&vth_s[nf * 16 + lr][c * 32 + kg * 8];
                const bf16x8 vlf = *(const bf16x8*)&vtl_s[nf * 16 + lr][c * 32 + kg * 8];
                oacc[nf] = __builtin_amdgcn_mfma_f32_16x16x32_bf16(pha, vhf, oacc[nf], 0, 0, 0);
                oacc[nf] = __builtin_amdgcn_mfma_f32_16x16x32_bf16(pha, vlf, oacc[nf], 0, 0, 0);
                oacc[nf] = __builtin_amdgcn_mfma_f32_16x16x32_bf16(pla, vhf, oacc[nf], 0, 0, 0);
            }
        }
        __syncthreads();   // kv/vt tiles consumed; safe to restage
    }

    // ---- epilogue: normalize, split, store ----
#pragma unroll
    for (int nf = 0; nf < 4; ++nf)
#pragma unroll
        for (int j = 0; j < 4; ++j) {
            const float v = oacc[nf][j] / l_r[j];
            const int srow = b * SEQ + s0 + w * 16 + kg * 4 + j;
            const int col  = h * DH + nf * 16 + lr;
            unsigned short hh, ll;
            split2(v, hh, ll);
            ah[(size_t)srow * 1024 + col] = hh;
            al[(size_t)srow * 1024 + col] = ll;
        }
}

// ---------------------------------------------------------------------------
extern "C" void kernel_launch(void* const* d_in, const int* in_sizes, int n_in,
                              void* d_out, int out_size, void* d_ws, size_t ws_size,
                              hipStream_t stream)
{
    const float* x      = (const float*)d_in[0];
    const float* enc    = (const float*)d_in[1];
    const float* w_attn = (const float*)d_in[2];
    const float* b_attn = (const float*)d_in[3];
    const float* w_vis  = (const float*)d_in[4];
    const float* b_vis  = (const float*)d_in[5];
    const float* w_proj = (const float*)d_in[6];
    const float* b_proj = (const float*)d_in[7];
    float* out = (float*)d_out;

    // ---- workspace (total 65,011,712 B — identical to validated round 3) ----
    char* base = (char*)d_ws;
    unsigned short* xh   = (unsigned short*)(base + 0);          // 8 MiB
    unsigned short* xl   = (unsigned short*)(base + 8388608);    // 8 MiB
    unsigned short* ench = (unsigned short*)(base + 16777216);   // 4.5 MiB
    unsigned short* encl = (unsigned short*)(base + 21495808);
    unsigned short* w1h  = (unsigned short*)(base + 26214400);   // 2 MiB each
    unsigned short* w1l  = (unsigned short*)(base + 28311552);
    unsigned short* w2h  = (unsigned short*)(base + 30408704);
    unsigned short* w2l  = (unsigned short*)(base + 32505856);
    unsigned short* w3h  = (unsigned short*)(base + 34603008);
    unsigned short* w3l  = (unsigned short*)(base + 36700160);
    unsigned short* qh   = (unsigned short*)(base + 38797312);   // 8 MiB
    unsigned short* ql   = (unsigned short*)(base + 47185920);
    unsigned short* kvh  = (unsigned short*)(base + 55574528);   // 4.5 MiB
    unsigned short* kvl  = (unsigned short*)(base + 60293120);   // ends 65011712
    // phase aliases:
    unsigned short* kvth = (unsigned short*)(base + 0);          // over xh/xl (dead after GEMM1)
    unsigned short* kvtl = (unsigned short*)(base + 4718592);
    unsigned short* atth = (unsigned short*)(base + 16777216);   // over ench/encl (dead after GEMM2)
    unsigned short* attl = (unsigned short*)(base + 26214400);   // over w1/w2 (dead after GEMM2)

    // ---- operand prep ----
    split_rm<<<(MQ  * 1024 / 4) / 256, 256, 0, stream>>>(x, xh, xl);
    split_rm<<<(MKV * 1024 / 4) / 256, 256, 0, stream>>>(enc, ench, encl);
    split_tr<<<dim3(32, 32), 256, 0, stream>>>(w_attn, 3 * D_MODEL, w1h, w1l); // q-slice
    split_tr<<<dim3(32, 32), 256, 0, stream>>>(w_vis,  D_MODEL, w2h, w2l);
    split_tr<<<dim3(32, 32), 256, 0, stream>>>(w_proj, D_MODEL, w3h, w3l);

    // ---- q = x @ w_attn[:, :D] + b_attn[:D]  -> bf16 hi/lo ----
    gemm_split_mfma<true><<<dim3(8, MQ / 128), 256, 0, stream>>>(
        xh, xl, w1h, w1l, b_attn, nullptr, qh, ql, MQ);
    // ---- kv = enc @ w_vis + b_vis  -> bf16 hi/lo ----
    gemm_split_mfma<true><<<dim3(8, MKV / 128), 256, 0, stream>>>(
        ench, encl, w2h, w2l, b_vis, nullptr, kvh, kvl, MKV);
    // ---- kv^T per (b,h): [64 d][576 t] ----
    transpose_hl<<<dim3(TKV / 64, BATCH * NHEAD), 256, 0, stream>>>(kvh, kvl, kvth, kvtl);
    // ---- attention (MFMA) -> bf16 hi/lo ----
    attn_mfma<<<dim3(SEQ / 64, BATCH * NHEAD), 256, 0, stream>>>(
        qh, ql, kvh, kvl, kvth, kvtl, atth, attl);
    // ---- out = att @ w_proj + b_proj (fp32) ----
    gemm_split_mfma<false><<<dim3(8, MQ / 128), 256, 0, stream>>>(
        atth, attl, w3h, w3l, b_proj, out, nullptr, nullptr, MQ);
}

// Round 8
// 284.876 us; speedup vs baseline: 2.8825x; 1.0969x over previous
//
#include <hip/hip_runtime.h>
#include <math.h>

#define D_MODEL 1024
#define NHEAD   16
#define DH      64
#define BATCH   4
#define SEQ     1024
#define TKV     576
#define MQ      (BATCH * SEQ)   // 4096
#define MKV     (BATCH * TKV)   // 2304
#define NT      (TKV / 64)      // 9 KV tiles

typedef __attribute__((ext_vector_type(8))) short bf16x8;
typedef __attribute__((ext_vector_type(4))) float f32x4;

// ---------------------------------------------------------------------------
// bf16 helpers (bit-level, RNE)
// ---------------------------------------------------------------------------
__device__ __forceinline__ unsigned short f2bf(float x) {
    unsigned int u = __float_as_uint(x);
    unsigned int r = (u + 0x7FFFu + ((u >> 16) & 1u)) >> 16;
    return (unsigned short)r;
}
__device__ __forceinline__ float bf2f(unsigned short b) {
    return __uint_as_float((unsigned int)b << 16);
}
__device__ __forceinline__ void split2(float x, unsigned short& h, unsigned short& l) {
    h = f2bf(x);
    l = f2bf(x - bf2f(h));   // residual ~2^-17 rel
}

// async global->LDS 16B copy; LDS dest = wave-uniform base + lane*16
__device__ __forceinline__ void async_copy16(const void* g, void* l) {
    auto gp = (const __attribute__((address_space(1))) unsigned int*)(g);
    auto lp = (__attribute__((address_space(3))) unsigned int*)(l);
    __builtin_amdgcn_global_load_lds(gp, lp, 16, 0, 0);
}

// ---------------------------------------------------------------------------
// split_rm: fp32 [M][K] row-major -> bf16 hi/lo [M][K]. One float4 per thread.
// ---------------------------------------------------------------------------
__global__ __launch_bounds__(256) void split_rm(
    const float* __restrict__ in,
    unsigned short* __restrict__ oh, unsigned short* __restrict__ ol)
{
    const size_t i = (size_t)blockIdx.x * 256 + threadIdx.x;
    const float4 v = reinterpret_cast<const float4*>(in)[i];
    ushort4 h, l;
    split2(v.x, h.x, l.x);
    split2(v.y, h.y, l.y);
    split2(v.z, h.z, l.z);
    split2(v.w, h.w, l.w);
    reinterpret_cast<ushort4*>(oh)[i] = h;
    reinterpret_cast<ushort4*>(ol)[i] = l;
}

// ---------------------------------------------------------------------------
// split_tr: W fp32 [K][N] (leading dim ld) -> Bt hi/lo bf16 [N][K=1024].
// ---------------------------------------------------------------------------
__global__ __launch_bounds__(256) void split_tr(
    const float* __restrict__ W, int ld,
    unsigned short* __restrict__ th, unsigned short* __restrict__ tl)
{
    __shared__ float sh[32][33];
    const int k0 = blockIdx.x * 32;
    const int n0 = blockIdx.y * 32;
    const int t  = threadIdx.x;
    const int r  = t >> 3;
    const int c4 = (t & 7) * 4;

    const float4 v = *reinterpret_cast<const float4*>(&W[(size_t)(k0 + r) * ld + n0 + c4]);
    sh[r][c4 + 0] = v.x;
    sh[r][c4 + 1] = v.y;
    sh[r][c4 + 2] = v.z;
    sh[r][c4 + 3] = v.w;
    __syncthreads();

    ushort4 h, l;
    split2(sh[c4 + 0][r], h.x, l.x);
    split2(sh[c4 + 1][r], h.y, l.y);
    split2(sh[c4 + 2][r], h.z, l.z);
    split2(sh[c4 + 3][r], h.w, l.w);
    *reinterpret_cast<ushort4*>(&th[(size_t)(n0 + r) * 1024 + k0 + c4]) = h;
    *reinterpret_cast<ushort4*>(&tl[(size_t)(n0 + r) * 1024 + k0 + c4]) = l;
}

// ---------------------------------------------------------------------------
// transpose_hl: kvh/kvl [B*T][1024] -> kvT [bh][64 d][576 t] (both hi & lo).
// ---------------------------------------------------------------------------
__global__ __launch_bounds__(256) void transpose_hl(
    const unsigned short* __restrict__ kvh, const unsigned short* __restrict__ kvl,
    unsigned short* __restrict__ kvth, unsigned short* __restrict__ kvtl)
{
    __shared__ __align__(16) unsigned short th_[64][72];   // [d][t]
    __shared__ __align__(16) unsigned short tl_[64][72];
    const int tid = threadIdx.x;
    const int t0  = blockIdx.x * 64;
    const int bh  = blockIdx.y;
    const int b   = bh >> 4;
    const int h   = bh & 15;

#pragma unroll
    for (int p = 0; p < 2; ++p) {
        const int idx = p * 256 + tid;
        const int rr  = idx >> 3;   // t within tile
        const int c   = idx & 7;    // 8-ushort chunk along d
        const size_t src = (size_t)(b * TKV + t0 + rr) * 1024 + h * DH + c * 8;
        const bf16x8 vh = *(const bf16x8*)&kvh[src];
        const bf16x8 vl = *(const bf16x8*)&kvl[src];
#pragma unroll
        for (int e = 0; e < 8; ++e) {
            th_[c * 8 + e][rr] = (unsigned short)vh[e];
            tl_[c * 8 + e][rr] = (unsigned short)vl[e];
        }
    }
    __syncthreads();

#pragma unroll
    for (int p = 0; p < 2; ++p) {
        const int idx = p * 256 + tid;
        const int d   = idx >> 3;
        const int c2  = idx & 7;
        const size_t dst = (size_t)(bh * 64 + d) * TKV + t0 + c2 * 8;
        *(bf16x8*)&kvth[dst] = *(const bf16x8*)&th_[d][c2 * 8];
        *(bf16x8*)&kvtl[dst] = *(const bf16x8*)&tl_[d][c2 * 8];
    }
}

// ---------------------------------------------------------------------------
// Split-bf16 MFMA GEMM, 2-phase double-buffered staging (T3 minimum pattern):
// stage(next) issued BEFORE compute(cur); single barrier per K-step.
// Race-free: stage(kt) targets the buffer whose reads finished before the
// barrier ending kt-1; the vmcnt(0) drain at each barrier guarantees the
// staged buffer is complete before any wave enters the next K-step.
// Frag/epilogue logic identical to the round-3/4 validated kernel.
// ---------------------------------------------------------------------------
template<bool BF16OUT>
__global__ __launch_bounds__(256) void gemm_split_mfma(
    const unsigned short* __restrict__ Ah, const unsigned short* __restrict__ Al,
    const unsigned short* __restrict__ Bth, const unsigned short* __restrict__ Btl,
    const float* __restrict__ bias,
    float* __restrict__ C,
    unsigned short* __restrict__ Ch, unsigned short* __restrict__ Cl,
    int M)
{
    __shared__ unsigned short lds[2][16384];   // [buf][ Ah | Al | Bh | Bl ] 8KB each

    const int tid  = threadIdx.x;
    const int lane = tid & 63;
    const int wv   = tid >> 6;

    // XCD-aware chunked block swizzle (gridDim.x == 8; nwg % 8 == 0)
    const int nwg = (gridDim.y << 3);
    const int lin = blockIdx.y * 8 + blockIdx.x;
    const int cpx = nwg >> 3;
    const int swz = (lin & 7) * cpx + (lin >> 3);
    const int brow = (swz >> 3) * 128;
    const int bcol = (swz & 7) * 128;

    const int wr = (wv >> 1) * 64;
    const int wc = (wv & 1) * 64;
    const int lr = lane & 15;
    const int kg = lane >> 4;

    f32x4 acc[4][4];
#pragma unroll
    for (int i = 0; i < 4; ++i)
#pragma unroll
        for (int j = 0; j < 4; ++j) acc[i][j] = (f32x4){0.f, 0.f, 0.f, 0.f};

    auto stage = [&](int buf, int k0) {
#pragma unroll
        for (int i = 0; i < 2; ++i) {
            const int ci = i * 256 + tid;
            const int r  = ci >> 2;
            const int c  = ci & 3;
            const size_t aoff = (size_t)(brow + r) * 1024 + k0 + c * 8;
            const size_t boff = (size_t)(bcol + r) * 1024 + k0 + c * 8;
            char* ldst = (char*)&lds[buf][0] + i * 4096 + wv * 1024;
            async_copy16(Ah  + aoff, ldst);
            async_copy16(Al  + aoff, ldst + 8192);
            async_copy16(Bth + boff, ldst + 16384);
            async_copy16(Btl + boff, ldst + 24576);
        }
    };

    stage(0, 0);
    __syncthreads();

    int cur = 0;
    for (int kt = 0; kt < 32; ++kt) {
        stage(cur ^ 1, ((kt + 1) & 31) << 5);   // wrap on last iter (harmless)

        const unsigned short* lAh = lds[cur];
        const unsigned short* lAl = lds[cur] + 4096;
        const unsigned short* lBh = lds[cur] + 8192;
        const unsigned short* lBl = lds[cur] + 12288;

        bf16x8 afh[4], afl[4], bfh[4], bfl[4];
#pragma unroll
        for (int f = 0; f < 4; ++f) {
            const int mb = (wr + f * 16 + lr) * 64 + kg * 16;
            const int nb = (wc + f * 16 + lr) * 64 + kg * 16;
            afh[f] = *(const bf16x8*)((const char*)lAh + mb);
            afl[f] = *(const bf16x8*)((const char*)lAl + mb);
            bfh[f] = *(const bf16x8*)((const char*)lBh + nb);
            bfl[f] = *(const bf16x8*)((const char*)lBl + nb);
        }

#pragma unroll
        for (int mf = 0; mf < 4; ++mf)
#pragma unroll
            for (int nf = 0; nf < 4; ++nf) {
                acc[mf][nf] = __builtin_amdgcn_mfma_f32_16x16x32_bf16(afh[mf], bfh[nf], acc[mf][nf], 0, 0, 0);
                acc[mf][nf] = __builtin_amdgcn_mfma_f32_16x16x32_bf16(afh[mf], bfl[nf], acc[mf][nf], 0, 0, 0);
                acc[mf][nf] = __builtin_amdgcn_mfma_f32_16x16x32_bf16(afl[mf], bfh[nf], acc[mf][nf], 0, 0, 0);
            }
        __syncthreads();
        cur ^= 1;
    }

    // epilogue. D: col=lane&15, row=(lane>>4)*4+reg (validated)
#pragma unroll
    for (int mf = 0; mf < 4; ++mf)
#pragma unroll
        for (int nf = 0; nf < 4; ++nf)
#pragma unroll
            for (int j = 0; j < 4; ++j) {
                const int row = brow + wr + mf * 16 + kg * 4 + j;
                const int col = bcol + wc + nf * 16 + lr;
                const float v = acc[mf][nf][j] + bias[col];
                if constexpr (BF16OUT) {
                    unsigned short hh, ll;
                    split2(v, hh, ll);
                    Ch[(size_t)row * 1024 + col] = hh;
                    Cl[(size_t)row * 1024 + col] = ll;
                } else {
                    C[(size_t)row * 1024 + col] = v;
                }
            }
}

// ---------------------------------------------------------------------------
// MFMA flash cross-attention, v2.
// 4 waves x 32 q-rows = 128 q-rows/block. Grid (SEQ/128=8, B*H=64).
// KV/V^T/P tiles in LDS with exact 128B rows + XOR chunk swizzle
// (chunk ^= row&7): every b128 access at the 8-lane/bank-quad structural
// minimum; P b16 writes ~4-way worst case (minor). T14: next KV tile loaded
// to regs during compute, ds_write after the consume barrier. exp2 softmax.
// __launch_bounds__(256,2): pin 2 blocks/CU (VGPR cap 256; est. ~180 live).
// ---------------------------------------------------------------------------
__global__ __launch_bounds__(256, 2) void attn_mfma(
    const unsigned short* __restrict__ qh, const unsigned short* __restrict__ ql,
    const unsigned short* __restrict__ kvh, const unsigned short* __restrict__ kvl,
    const unsigned short* __restrict__ kvth, const unsigned short* __restrict__ kvtl,
    unsigned short* __restrict__ ah, unsigned short* __restrict__ al)
{
    __shared__ __align__(16) unsigned short kh_s[64][64],  kl_s[64][64];
    __shared__ __align__(16) unsigned short vth_s[64][64], vtl_s[64][64];
    __shared__ __align__(16) unsigned short ph_s[4][32][64], pl_s[4][32][64];

    const int tid  = threadIdx.x;
    const int lane = tid & 63;
    const int w    = tid >> 6;
    const int lr   = lane & 15;
    const int kg   = lane >> 4;
    const int s0   = blockIdx.x * 128;
    const int bh   = blockIdx.y;
    const int b    = bh >> 4;
    const int h    = bh & 15;

    // staging coords: thread covers rows tid>>3 and tid>>3+32, chunk tid&7
    const int r0 = tid >> 3;
    const int c0 = tid & 7;

    // ---- Q fragments, hoisted: [group][c-half] ----
    bf16x8 qhf[2][2], qlf[2][2];
#pragma unroll
    for (int g = 0; g < 2; ++g) {
        const size_t qoff = (size_t)(b * SEQ + s0 + w * 32 + g * 16 + lr) * 1024 + h * DH;
#pragma unroll
        for (int c = 0; c < 2; ++c) {
            qhf[g][c] = *(const bf16x8*)&qh[qoff + c * 32 + kg * 8];
            qlf[g][c] = *(const bf16x8*)&ql[qoff + c * 32 + kg * 8];
        }
    }

    f32x4 oacc[2][4];
#pragma unroll
    for (int g = 0; g < 2; ++g)
#pragma unroll
        for (int nf = 0; nf < 4; ++nf) oacc[g][nf] = (f32x4){0.f, 0.f, 0.f, 0.f};
    float m2[2][4], lsum[2][4];
#pragma unroll
    for (int g = 0; g < 2; ++g)
#pragma unroll
        for (int j = 0; j < 4; ++j) { m2[g][j] = -INFINITY; lsum[g][j] = 0.f; }

    // T14 staging registers (next tile)
    bf16x8 nkh[2], nkl[2], nvh[2], nvl[2];

    auto ld_tile = [&](int it) {
#pragma unroll
        for (int i = 0; i < 2; ++i) {
            const int rr = r0 + i * 32;
            const size_t kvo = (size_t)(b * TKV + it * 64 + rr) * 1024 + h * DH + c0 * 8;
            const size_t vto = (size_t)(bh * 64 + rr) * TKV + it * 64 + c0 * 8;
            nkh[i] = *(const bf16x8*)&kvh[kvo];
            nkl[i] = *(const bf16x8*)&kvl[kvo];
            nvh[i] = *(const bf16x8*)&kvth[vto];
            nvl[i] = *(const bf16x8*)&kvtl[vto];
        }
    };
    auto st_tile = [&]() {
#pragma unroll
        for (int i = 0; i < 2; ++i) {
            const int rr = r0 + i * 32;
            const int sc = (c0 ^ (rr & 7)) * 8;   // swizzled chunk
            *(bf16x8*)&kh_s[rr][sc]  = nkh[i];
            *(bf16x8*)&kl_s[rr][sc]  = nkl[i];
            *(bf16x8*)&vth_s[rr][sc] = nvh[i];
            *(bf16x8*)&vtl_s[rr][sc] = nvl[i];
        }
    };

    ld_tile(0);
    st_tile();
    __syncthreads();

    const float SC2 = 0.125f * 1.44269504089f;   // score scale * log2(e)

    for (int it = 0; it < NT; ++it) {
        if (it + 1 < NT) ld_tile(it + 1);   // loads fly under the compute below

        // ---- QK^T: S[32 s][64 t], 3-term split; K-frags shared across groups
        f32x4 sacc[2][4];
#pragma unroll
        for (int g = 0; g < 2; ++g)
#pragma unroll
            for (int nf = 0; nf < 4; ++nf) sacc[g][nf] = (f32x4){0.f, 0.f, 0.f, 0.f};
#pragma unroll
        for (int c = 0; c < 2; ++c) {
            const int ch = (((c << 2) | kg) ^ (lr & 7)) << 3;   // swizzled ushort idx
#pragma unroll
            for (int nf = 0; nf < 4; ++nf) {
                const bf16x8 bhf = *(const bf16x8*)&kh_s[nf * 16 + lr][ch];
                const bf16x8 blf = *(const bf16x8*)&kl_s[nf * 16 + lr][ch];
#pragma unroll
                for (int g = 0; g < 2; ++g) {
                    sacc[g][nf] = __builtin_amdgcn_mfma_f32_16x16x32_bf16(qhf[g][c], bhf, sacc[g][nf], 0, 0, 0);
                    sacc[g][nf] = __builtin_amdgcn_mfma_f32_16x16x32_bf16(qhf[g][c], blf, sacc[g][nf], 0, 0, 0);
                    sacc[g][nf] = __builtin_amdgcn_mfma_f32_16x16x32_bf16(qlf[g][c], bhf, sacc[g][nf], 0, 0, 0);
                }
            }
        }

        // ---- online softmax (exp2 domain), C-layout row = kg*4+j, col = nf*16+lr
#pragma unroll
        for (int g = 0; g < 2; ++g)
#pragma unroll
            for (int j = 0; j < 4; ++j) {
                const float s0v = sacc[g][0][j] * SC2;
                const float s1v = sacc[g][1][j] * SC2;
                const float s2v = sacc[g][2][j] * SC2;
                const float s3v = sacc[g][3][j] * SC2;
                float mx = fmaxf(fmaxf(s0v, s1v), fmaxf(s2v, s3v));
                mx = fmaxf(mx, __shfl_xor(mx, 1));
                mx = fmaxf(mx, __shfl_xor(mx, 2));
                mx = fmaxf(mx, __shfl_xor(mx, 4));
                mx = fmaxf(mx, __shfl_xor(mx, 8));
                const float mnew = fmaxf(m2[g][j], mx);
                const float corr = exp2f(m2[g][j] - mnew);   // 0 on first tile
                const float p0 = exp2f(s0v - mnew);
                const float p1 = exp2f(s1v - mnew);
                const float p2 = exp2f(s2v - mnew);
                const float p3 = exp2f(s3v - mnew);
                float ps = p0 + p1 + p2 + p3;
                ps += __shfl_xor(ps, 1);
                ps += __shfl_xor(ps, 2);
                ps += __shfl_xor(ps, 4);
                ps += __shfl_xor(ps, 8);
                lsum[g][j] = lsum[g][j] * corr + ps;
                m2[g][j] = mnew;
#pragma unroll
                for (int nf = 0; nf < 4; ++nf) oacc[g][nf][j] *= corr;
                // P store, swizzled chunks (write row key = prow&7)
                const int prow = g * 16 + kg * 4 + j;
                const int key  = prow & 7;
                const int lo3  = lr & 7;
                const int hi1  = lr >> 3;
                unsigned short hh, ll;
                split2(p0, hh, ll);
                ph_s[w][prow][((0 + hi1) ^ key) * 8 + lo3] = hh;
                pl_s[w][prow][((0 + hi1) ^ key) * 8 + lo3] = ll;
                split2(p1, hh, ll);
                ph_s[w][prow][((2 + hi1) ^ key) * 8 + lo3] = hh;
                pl_s[w][prow][((2 + hi1) ^ key) * 8 + lo3] = ll;
                split2(p2, hh, ll);
                ph_s[w][prow][((4 + hi1) ^ key) * 8 + lo3] = hh;
                pl_s[w][prow][((4 + hi1) ^ key) * 8 + lo3] = ll;
                split2(p3, hh, ll);
                ph_s[w][prow][((6 + hi1) ^ key) * 8 + lo3] = hh;
                pl_s[w][prow][((6 + hi1) ^ key) * 8 + lo3] = ll;
            }

        // ---- PV: O[32 s][64 d] += P @ V; V-frags shared across groups ----
        // (P wave-local: same-wave DS ordering, no barrier needed)
#pragma unroll
        for (int c = 0; c < 2; ++c) {
            const int ch = (((c << 2) | kg) ^ (lr & 7)) << 3;
            bf16x8 pha[2], pla[2];
#pragma unroll
            for (int g = 0; g < 2; ++g) {
                pha[g] = *(const bf16x8*)&ph_s[w][g * 16 + lr][ch];
                pla[g] = *(const bf16x8*)&pl_s[w][g * 16 + lr][ch];
            }
#pragma unroll
            for (int nf = 0; nf < 4; ++nf) {
                const bf16x8 vhf = *(const bf16x8*)&vth_s[nf * 16 + lr][ch];
                const bf16x8 vlf = *(const bf16x8*)&vtl_s[nf * 16 + lr][ch];
#pragma unroll
                for (int g = 0; g < 2; ++g) {
                    oacc[g][nf] = __builtin_amdgcn_mfma_f32_16x16x32_bf16(pha[g], vhf, oacc[g][nf], 0, 0, 0);
                    oacc[g][nf] = __builtin_amdgcn_mfma_f32_16x16x32_bf16(pha[g], vlf, oacc[g][nf], 0, 0, 0);
                    oacc[g][nf] = __builtin_amdgcn_mfma_f32_16x16x32_bf16(pla[g], vhf, oacc[g][nf], 0, 0, 0);
                }
            }
        }

        __syncthreads();                    // all waves done reading K/V LDS
        if (it + 1 < NT) st_tile();         // write next tile (waits its vmcnt)
        __syncthreads();                    // writes visible
    }

    // ---- epilogue: normalize, split, store ----
#pragma unroll
    for (int g = 0; g < 2; ++g)
#pragma unroll
        for (int nf = 0; nf < 4; ++nf)
#pragma unroll
            for (int j = 0; j < 4; ++j) {
                const float v = oacc[g][nf][j] / lsum[g][j];
                const int srow = b * SEQ + s0 + w * 32 + g * 16 + kg * 4 + j;
                const int col  = h * DH + nf * 16 + lr;
                unsigned short hh, ll;
                split2(v, hh, ll);
                ah[(size_t)srow * 1024 + col] = hh;
                al[(size_t)srow * 1024 + col] = ll;
            }
}

// ---------------------------------------------------------------------------
extern "C" void kernel_launch(void* const* d_in, const int* in_sizes, int n_in,
                              void* d_out, int out_size, void* d_ws, size_t ws_size,
                              hipStream_t stream)
{
    const float* x      = (const float*)d_in[0];
    const float* enc    = (const float*)d_in[1];
    const float* w_attn = (const float*)d_in[2];
    const float* b_attn = (const float*)d_in[3];
    const float* w_vis  = (const float*)d_in[4];
    const float* b_vis  = (const float*)d_in[5];
    const float* w_proj = (const float*)d_in[6];
    const float* b_proj = (const float*)d_in[7];
    float* out = (float*)d_out;

    // ---- workspace (total 65,011,712 B — identical to validated rounds) ----
    char* base = (char*)d_ws;
    unsigned short* xh   = (unsigned short*)(base + 0);          // 8 MiB
    unsigned short* xl   = (unsigned short*)(base + 8388608);    // 8 MiB
    unsigned short* ench = (unsigned short*)(base + 16777216);   // 4.5 MiB
    unsigned short* encl = (unsigned short*)(base + 21495808);
    unsigned short* w1h  = (unsigned short*)(base + 26214400);   // 2 MiB each
    unsigned short* w1l  = (unsigned short*)(base + 28311552);
    unsigned short* w2h  = (unsigned short*)(base + 30408704);
    unsigned short* w2l  = (unsigned short*)(base + 32505856);
    unsigned short* w3h  = (unsigned short*)(base + 34603008);
    unsigned short* w3l  = (unsigned short*)(base + 36700160);
    unsigned short* qh   = (unsigned short*)(base + 38797312);   // 8 MiB
    unsigned short* ql   = (unsigned short*)(base + 47185920);
    unsigned short* kvh  = (unsigned short*)(base + 55574528);   // 4.5 MiB
    unsigned short* kvl  = (unsigned short*)(base + 60293120);   // ends 65011712
    // phase aliases:
    unsigned short* kvth = (unsigned short*)(base + 0);          // over xh/xl (dead after GEMM1)
    unsigned short* kvtl = (unsigned short*)(base + 4718592);
    unsigned short* atth = (unsigned short*)(base + 16777216);   // over ench/encl (dead after GEMM2)
    unsigned short* attl = (unsigned short*)(base + 26214400);   // over w1/w2 (dead after GEMM2)

    // ---- operand prep ----
    split_rm<<<(MQ  * 1024 / 4) / 256, 256, 0, stream>>>(x, xh, xl);
    split_rm<<<(MKV * 1024 / 4) / 256, 256, 0, stream>>>(enc, ench, encl);
    split_tr<<<dim3(32, 32), 256, 0, stream>>>(w_attn, 3 * D_MODEL, w1h, w1l); // q-slice
    split_tr<<<dim3(32, 32), 256, 0, stream>>>(w_vis,  D_MODEL, w2h, w2l);
    split_tr<<<dim3(32, 32), 256, 0, stream>>>(w_proj, D_MODEL, w3h, w3l);

    // ---- q = x @ w_attn[:, :D] + b_attn[:D]  -> bf16 hi/lo ----
    gemm_split_mfma<true><<<dim3(8, MQ / 128), 256, 0, stream>>>(
        xh, xl, w1h, w1l, b_attn, nullptr, qh, ql, MQ);
    // ---- kv = enc @ w_vis + b_vis  -> bf16 hi/lo ----
    gemm_split_mfma<true><<<dim3(8, MKV / 128), 256, 0, stream>>>(
        ench, encl, w2h, w2l, b_vis, nullptr, kvh, kvl, MKV);
    // ---- kv^T per (b,h): [64 d][576 t] ----
    transpose_hl<<<dim3(TKV / 64, BATCH * NHEAD), 256, 0, stream>>>(kvh, kvl, kvth, kvtl);
    // ---- attention (MFMA) -> bf16 hi/lo ----
    attn_mfma<<<dim3(SEQ / 128, BATCH * NHEAD), 256, 0, stream>>>(
        qh, ql, kvh, kvl, kvth, kvtl, atth, attl);
    // ---- out = att @ w_proj + b_proj (fp32) ----
    gemm_split_mfma<false><<<dim3(8, MQ / 128), 256, 0, stream>>>(
        atth, attl, w3h, w3l, b_proj, out, nullptr, nullptr, MQ);
}

// Round 12
// 242.018 us; speedup vs baseline: 3.3929x; 1.1771x over previous
//
#include <hip/hip_runtime.h>
#include <math.h>

#define D_MODEL 1024
#define NHEAD   16
#define DH      64
#define BATCH   4
#define SEQ     1024
#define TKV     576
#define MQ      (BATCH * SEQ)   // 4096
#define MKV     (BATCH * TKV)   // 2304
#define NT      (TKV / 64)      // 9 KV tiles

typedef __attribute__((ext_vector_type(8))) short bf16x8;
typedef __attribute__((ext_vector_type(4))) float f32x4;

// ---------------------------------------------------------------------------
// bf16 helpers (bit-level, RNE)
// ---------------------------------------------------------------------------
__device__ __forceinline__ unsigned short f2bf(float x) {
    unsigned int u = __float_as_uint(x);
    unsigned int r = (u + 0x7FFFu + ((u >> 16) & 1u)) >> 16;
    return (unsigned short)r;
}
__device__ __forceinline__ float bf2f(unsigned short b) {
    return __uint_as_float((unsigned int)b << 16);
}
__device__ __forceinline__ void split2(float x, unsigned short& h, unsigned short& l) {
    h = f2bf(x);
    l = f2bf(x - bf2f(h));   // residual ~2^-17 rel
}

// async global->LDS 16B copy; LDS dest = wave-uniform base + lane*16
__device__ __forceinline__ void async_copy16(const void* g, void* l) {
    auto gp = (const __attribute__((address_space(1))) unsigned int*)(g);
    auto lp = (__attribute__((address_space(3))) unsigned int*)(l);
    __builtin_amdgcn_global_load_lds(gp, lp, 16, 0, 0);
}

// ---------------------------------------------------------------------------
// split_rm: fp32 [M][K] row-major -> bf16 hi/lo [M][K]. One float4 per thread.
// ---------------------------------------------------------------------------
__global__ __launch_bounds__(256) void split_rm(
    const float* __restrict__ in,
    unsigned short* __restrict__ oh, unsigned short* __restrict__ ol)
{
    const size_t i = (size_t)blockIdx.x * 256 + threadIdx.x;
    const float4 v = reinterpret_cast<const float4*>(in)[i];
    ushort4 h, l;
    split2(v.x, h.x, l.x);
    split2(v.y, h.y, l.y);
    split2(v.z, h.z, l.z);
    split2(v.w, h.w, l.w);
    reinterpret_cast<ushort4*>(oh)[i] = h;
    reinterpret_cast<ushort4*>(ol)[i] = l;
}

// ---------------------------------------------------------------------------
// split_tr: W fp32 [K][N] (leading dim ld) -> Bt hi/lo bf16 [N][K=1024].
// ---------------------------------------------------------------------------
__global__ __launch_bounds__(256) void split_tr(
    const float* __restrict__ W, int ld,
    unsigned short* __restrict__ th, unsigned short* __restrict__ tl)
{
    __shared__ float sh[32][33];
    const int k0 = blockIdx.x * 32;
    const int n0 = blockIdx.y * 32;
    const int t  = threadIdx.x;
    const int r  = t >> 3;
    const int c4 = (t & 7) * 4;

    const float4 v = *reinterpret_cast<const float4*>(&W[(size_t)(k0 + r) * ld + n0 + c4]);
    sh[r][c4 + 0] = v.x;
    sh[r][c4 + 1] = v.y;
    sh[r][c4 + 2] = v.z;
    sh[r][c4 + 3] = v.w;
    __syncthreads();

    ushort4 h, l;
    split2(sh[c4 + 0][r], h.x, l.x);
    split2(sh[c4 + 1][r], h.y, l.y);
    split2(sh[c4 + 2][r], h.z, l.z);
    split2(sh[c4 + 3][r], h.w, l.w);
    *reinterpret_cast<ushort4*>(&th[(size_t)(n0 + r) * 1024 + k0 + c4]) = h;
    *reinterpret_cast<ushort4*>(&tl[(size_t)(n0 + r) * 1024 + k0 + c4]) = l;
}

// ---------------------------------------------------------------------------
// transpose_perm: kvh/kvl [B*T][1024] -> V^T PERMUTED:
// vp[bh][d][tile][64 slots], slot q*32+kg*8+e holds V^T[d][t0 + 32q + kg*4
// + (e&3) + 16*(e>>2)] — the exact k-slot order PV's in-register P B-frags
// use, so attention can async-stage V with plain chunk swizzle + b128 reads.
// ---------------------------------------------------------------------------
__global__ __launch_bounds__(256) void transpose_perm(
    const unsigned short* __restrict__ kvh, const unsigned short* __restrict__ kvl,
    unsigned short* __restrict__ vph, unsigned short* __restrict__ vpl)
{
    __shared__ __align__(16) unsigned short th_[64][72];   // [d][t]
    __shared__ __align__(16) unsigned short tl_[64][72];
    const int tid = threadIdx.x;
    const int it  = blockIdx.x;          // tile index 0..8
    const int t0  = it * 64;
    const int bh  = blockIdx.y;
    const int b   = bh >> 4;
    const int h   = bh & 15;

#pragma unroll
    for (int p = 0; p < 2; ++p) {
        const int idx = p * 256 + tid;
        const int rr  = idx >> 3;   // t within tile
        const int c   = idx & 7;    // 8-ushort chunk along d
        const size_t src = (size_t)(b * TKV + t0 + rr) * 1024 + h * DH + c * 8;
        const bf16x8 vh = *(const bf16x8*)&kvh[src];
        const bf16x8 vl = *(const bf16x8*)&kvl[src];
#pragma unroll
        for (int e = 0; e < 8; ++e) {
            th_[c * 8 + e][rr] = (unsigned short)vh[e];
            tl_[c * 8 + e][rr] = (unsigned short)vl[e];
        }
    }
    __syncthreads();

#pragma unroll
    for (int p = 0; p < 2; ++p) {
        const int idx = p * 256 + tid;
        const int d   = idx >> 3;
        const int lc  = idx & 7;     // 16B chunk in output row
        const int q   = lc >> 2;
        const int kg  = lc & 3;
        const ushort4 a  = *(const ushort4*)&th_[d][32 * q + kg * 4];
        const ushort4 bb = *(const ushort4*)&th_[d][32 * q + 16 + kg * 4];
        const ushort4 a2  = *(const ushort4*)&tl_[d][32 * q + kg * 4];
        const ushort4 bb2 = *(const ushort4*)&tl_[d][32 * q + 16 + kg * 4];
        bf16x8 oh_, ol_;
        oh_[0] = (short)a.x;  oh_[1] = (short)a.y;  oh_[2] = (short)a.z;  oh_[3] = (short)a.w;
        oh_[4] = (short)bb.x; oh_[5] = (short)bb.y; oh_[6] = (short)bb.z; oh_[7] = (short)bb.w;
        ol_[0] = (short)a2.x;  ol_[1] = (short)a2.y;  ol_[2] = (short)a2.z;  ol_[3] = (short)a2.w;
        ol_[4] = (short)bb2.x; ol_[5] = (short)bb2.y; ol_[6] = (short)bb2.z; ol_[7] = (short)bb2.w;
        const size_t dst = ((size_t)(bh * 64 + d) * NT + it) * 64 + lc * 8;
        *(bf16x8*)&vph[dst] = oh_;
        *(bf16x8*)&vpl[dst] = ol_;
    }
}

// ---------------------------------------------------------------------------
// Split-bf16 MFMA GEMM core (shared by single and merged variants).
// 2-phase double-buffered staging; validated rounds 3/4/8.
// ---------------------------------------------------------------------------
template<bool BF16OUT>
__device__ __forceinline__ void gemm_body(
    const unsigned short* Ah, const unsigned short* Al,
    const unsigned short* Bth, const unsigned short* Btl,
    const float* bias, float* C,
    unsigned short* Ch, unsigned short* Cl,
    int brow, int bcol, unsigned short* lds /* 2*16384 ushorts */)
{
    const int tid  = threadIdx.x;
    const int lane = tid & 63;
    const int wv   = tid >> 6;
    const int wr = (wv >> 1) * 64;
    const int wc = (wv & 1) * 64;
    const int lr = lane & 15;
    const int kg = lane >> 4;

    f32x4 acc[4][4];
#pragma unroll
    for (int i = 0; i < 4; ++i)
#pragma unroll
        for (int j = 0; j < 4; ++j) acc[i][j] = (f32x4){0.f, 0.f, 0.f, 0.f};

    auto stage = [&](int buf, int k0) {
#pragma unroll
        for (int i = 0; i < 2; ++i) {
            const int ci = i * 256 + tid;
            const int r  = ci >> 2;
            const int c  = ci & 3;
            const size_t aoff = (size_t)(brow + r) * 1024 + k0 + c * 8;
            const size_t boff = (size_t)(bcol + r) * 1024 + k0 + c * 8;
            char* ldst = (char*)lds + buf * 32768 + i * 4096 + wv * 1024;
            async_copy16(Ah  + aoff, ldst);
            async_copy16(Al  + aoff, ldst + 8192);
            async_copy16(Bth + boff, ldst + 16384);
            async_copy16(Btl + boff, ldst + 24576);
        }
    };

    stage(0, 0);
    __syncthreads();

    int cur = 0;
    for (int kt = 0; kt < 32; ++kt) {
        stage(cur ^ 1, ((kt + 1) & 31) << 5);

        const unsigned short* lAh = lds + cur * 16384;
        const unsigned short* lAl = lAh + 4096;
        const unsigned short* lBh = lAh + 8192;
        const unsigned short* lBl = lAh + 12288;

        bf16x8 afh[4], afl[4], bfh[4], bfl[4];
#pragma unroll
        for (int f = 0; f < 4; ++f) {
            const int mb = (wr + f * 16 + lr) * 64 + kg * 16;
            const int nb = (wc + f * 16 + lr) * 64 + kg * 16;
            afh[f] = *(const bf16x8*)((const char*)lAh + mb);
            afl[f] = *(const bf16x8*)((const char*)lAl + mb);
            bfh[f] = *(const bf16x8*)((const char*)lBh + nb);
            bfl[f] = *(const bf16x8*)((const char*)lBl + nb);
        }

#pragma unroll
        for (int mf = 0; mf < 4; ++mf)
#pragma unroll
            for (int nf = 0; nf < 4; ++nf) {
                acc[mf][nf] = __builtin_amdgcn_mfma_f32_16x16x32_bf16(afh[mf], bfh[nf], acc[mf][nf], 0, 0, 0);
                acc[mf][nf] = __builtin_amdgcn_mfma_f32_16x16x32_bf16(afh[mf], bfl[nf], acc[mf][nf], 0, 0, 0);
                acc[mf][nf] = __builtin_amdgcn_mfma_f32_16x16x32_bf16(afl[mf], bfh[nf], acc[mf][nf], 0, 0, 0);
            }
        __syncthreads();
        cur ^= 1;
    }

#pragma unroll
    for (int mf = 0; mf < 4; ++mf)
#pragma unroll
        for (int nf = 0; nf < 4; ++nf)
#pragma unroll
            for (int j = 0; j < 4; ++j) {
                const int row = brow + wr + mf * 16 + kg * 4 + j;
                const int col = bcol + wc + nf * 16 + lr;
                const float v = acc[mf][nf][j] + bias[col];
                if constexpr (BF16OUT) {
                    unsigned short hh, ll;
                    split2(v, hh, ll);
                    Ch[(size_t)row * 1024 + col] = hh;
                    Cl[(size_t)row * 1024 + col] = ll;
                } else {
                    C[(size_t)row * 1024 + col] = v;
                }
            }
}

// Single GEMM (fp32 out) — used for the final projection.
__global__ __launch_bounds__(256) void gemm_split_mfma_f32(
    const unsigned short* __restrict__ Ah, const unsigned short* __restrict__ Al,
    const unsigned short* __restrict__ Bth, const unsigned short* __restrict__ Btl,
    const float* __restrict__ bias, float* __restrict__ C)
{
    __shared__ unsigned short lds[2 * 16384];
    const int nwg = (gridDim.y << 3);
    const int lin = blockIdx.y * 8 + blockIdx.x;
    const int cpx = nwg >> 3;
    const int swz = (lin & 7) * cpx + (lin >> 3);
    gemm_body<false>(Ah, Al, Bth, Btl, bias, C, nullptr, nullptr,
                     (swz >> 3) * 128, (swz & 7) * 128, lds);
}

// Merged GEMM1+GEMM2 (both bf16-out): grid (8, 50); row-blocks 0..31 -> seg1
// (M=4096), 32..49 -> seg2 (M=2304). Fixes the half-empty-machine problem.
__global__ __launch_bounds__(256) void gemm12_split_mfma(
    const unsigned short* __restrict__ A1h, const unsigned short* __restrict__ A1l,
    const unsigned short* __restrict__ B1h, const unsigned short* __restrict__ B1l,
    const float* __restrict__ bias1,
    unsigned short* __restrict__ C1h, unsigned short* __restrict__ C1l,
    const unsigned short* __restrict__ A2h, const unsigned short* __restrict__ A2l,
    const unsigned short* __restrict__ B2h, const unsigned short* __restrict__ B2l,
    const float* __restrict__ bias2,
    unsigned short* __restrict__ C2h, unsigned short* __restrict__ C2l)
{
    __shared__ unsigned short lds[2 * 16384];
    const int nwg = (gridDim.y << 3);                 // 400
    const int lin = blockIdx.y * 8 + blockIdx.x;
    const int cpx = nwg >> 3;                         // 50
    const int swz = (lin & 7) * cpx + (lin >> 3);     // bijective (400 % 8 == 0)
    const int ridx = swz >> 3;
    const int bcol = (swz & 7) * 128;
    if (ridx < 32) {
        gemm_body<true>(A1h, A1l, B1h, B1l, bias1, nullptr, C1h, C1l,
                        ridx * 128, bcol, lds);
    } else {
        gemm_body<true>(A2h, A2l, B2h, B2l, bias2, nullptr, C2h, C2l,
                        (ridx - 32) * 128, bcol, lds);
    }
}

// ---------------------------------------------------------------------------
// MFMA flash cross-attention v3 — swapped-operand structure.
// S^T = mfma(A=K, B=Q): lane owns q-col s=lr, 16 t-values in regs per kf-set.
// Softmax: 15 in-reg max + 2 shfl (xor 16/32 across kg). P stays IN REGISTERS:
// P^T B-frags assemble from own-lane p-values; V^T pre-permuted to match the
// k-slot order (transpose_perm). PV = mfma(A=V^T, B=P^T) -> O^T; corr/lsum
// lane-uniform per s. LDS 32KB (K+V only), chunk-XOR swizzled, staged fully
// async: K(i+1) during softmax+PV(i); V(i+1) during QK(i+1). 3 blocks/CU.
// ---------------------------------------------------------------------------
__global__ __launch_bounds__(256, 3) void attn_mfma(
    const unsigned short* __restrict__ qh, const unsigned short* __restrict__ ql,
    const unsigned short* __restrict__ kvh, const unsigned short* __restrict__ kvl,
    const unsigned short* __restrict__ vph, const unsigned short* __restrict__ vpl,
    unsigned short* __restrict__ ah, unsigned short* __restrict__ al)
{
    __shared__ __align__(16) unsigned short smem[4 * 4096];  // kh|kl|vh|vl 8KB each

    const int tid  = threadIdx.x;
    const int lane = tid & 63;
    const int w    = tid >> 6;
    const int lr   = lane & 15;
    const int kg   = lane >> 4;
    const int s0   = blockIdx.x * 128;
    const int bh   = blockIdx.y;
    const int b    = bh >> 4;
    const int h    = bh & 15;
    const int rr0  = tid >> 3;   // staging row 0..31 (+32)
    const int cc   = tid & 7;    // staging physical chunk

    // content at physical chunk (row, cc) = logical chunk cc ^ (row&7)
    auto stageK = [&](int it) {
#pragma unroll
        for (int i = 0; i < 2; ++i) {
            const int rr = rr0 + i * 32;
            const int lc = cc ^ (rr & 7);
            const size_t src = (size_t)(b * TKV + it * 64 + rr) * 1024 + h * DH + lc * 8;
            char* dst = (char*)smem + i * 4096 + w * 1024;
            async_copy16(kvh + src, dst);
            async_copy16(kvl + src, dst + 8192);
        }
    };
    auto stageV = [&](int it) {
#pragma unroll
        for (int i = 0; i < 2; ++i) {
            const int rr = rr0 + i * 32;               // d row
            const int lc = cc ^ (rr & 7);
            const size_t src = ((size_t)(bh * 64 + rr) * NT + it) * 64 + lc * 8;
            char* dst = (char*)smem + 16384 + i * 4096 + w * 1024;
            async_copy16(vph + src, dst);
            async_copy16(vpl + src, dst + 8192);
        }
    };

    // ---- Q B-frags, hoisted: rows s = w*32 + g*16 + lr ----
    bf16x8 qhf[2][2], qlf[2][2];
#pragma unroll
    for (int g = 0; g < 2; ++g) {
        const size_t qoff = (size_t)(b * SEQ + s0 + w * 32 + g * 16 + lr) * 1024 + h * DH;
#pragma unroll
        for (int c = 0; c < 2; ++c) {
            qhf[g][c] = *(const bf16x8*)&qh[qoff + c * 32 + kg * 8];
            qlf[g][c] = *(const bf16x8*)&ql[qoff + c * 32 + kg * 8];
        }
    }

    f32x4 oacc[2][4];   // [g][df]: O^T frag, lane: d=df*16+kg*4+j, s=g*16+lr
#pragma unroll
    for (int g = 0; g < 2; ++g)
#pragma unroll
        for (int df = 0; df < 4; ++df) oacc[g][df] = (f32x4){0.f, 0.f, 0.f, 0.f};
    float m2[2]   = {-INFINITY, -INFINITY};
    float lsum[2] = {0.f, 0.f};

    stageK(0);
    stageV(0);
    __syncthreads();

    const float SC2 = 0.125f * 1.44269504089f;   // 1/sqrt(64) * log2(e)

    for (int it = 0; it < NT; ++it) {
        // ---- QK^T (swapped): sacc[g][kf] = S^T tile, t=kf*16+kg*4+j, s=lr ----
        f32x4 sacc[2][4];
#pragma unroll
        for (int g = 0; g < 2; ++g)
#pragma unroll
            for (int kf = 0; kf < 4; ++kf) sacc[g][kf] = (f32x4){0.f, 0.f, 0.f, 0.f};
#pragma unroll
        for (int c = 0; c < 2; ++c)
#pragma unroll
            for (int kf = 0; kf < 4; ++kf) {
                const int ka = (kf * 16 + lr) * 128 + ((((c << 2) | kg) ^ (lr & 7)) << 4);
                const bf16x8 akh = *(const bf16x8*)((const char*)smem + ka);
                const bf16x8 akl = *(const bf16x8*)((const char*)smem + 8192 + ka);
#pragma unroll
                for (int g = 0; g < 2; ++g) {
                    sacc[g][kf] = __builtin_amdgcn_mfma_f32_16x16x32_bf16(akh, qhf[g][c], sacc[g][kf], 0, 0, 0);
                    sacc[g][kf] = __builtin_amdgcn_mfma_f32_16x16x32_bf16(akh, qlf[g][c], sacc[g][kf], 0, 0, 0);
                    sacc[g][kf] = __builtin_amdgcn_mfma_f32_16x16x32_bf16(akl, qhf[g][c], sacc[g][kf], 0, 0, 0);
                }
            }

        __syncthreads();                 // all waves done reading K (and V staged)
        if (it + 1 < NT) stageK(it + 1); // K(i+1) flies under softmax+PV

        // ---- softmax (exp2 domain) + in-register P pack ----
        bf16x8 pbh[2][2], pbl[2][2];
#pragma unroll
        for (int g = 0; g < 2; ++g) {
            float p[16];
            float mx = -INFINITY;
#pragma unroll
            for (int kf = 0; kf < 4; ++kf)
#pragma unroll
                for (int j = 0; j < 4; ++j) {
                    p[kf * 4 + j] = sacc[g][kf][j] * SC2;
                    mx = fmaxf(mx, p[kf * 4 + j]);
                }
            mx = fmaxf(mx, __shfl_xor(mx, 16));
            mx = fmaxf(mx, __shfl_xor(mx, 32));
            const float mnew = fmaxf(m2[g], mx);
            const float corr = exp2f(m2[g] - mnew);   // 0 on first tile
            float ps = 0.f;
#pragma unroll
            for (int i = 0; i < 16; ++i) { p[i] = exp2f(p[i] - mnew); ps += p[i]; }
            ps += __shfl_xor(ps, 16);
            ps += __shfl_xor(ps, 32);
            lsum[g] = lsum[g] * corr + ps;
            m2[g] = mnew;
#pragma unroll
            for (int df = 0; df < 4; ++df)
#pragma unroll
                for (int j = 0; j < 4; ++j) oacc[g][df][j] *= corr;
            // B-frag slot e at chunk q <-> t = 32q + 16*(e>>2) + kg*4 + (e&3)
            //                            = p[(2q + (e>>2))*4 + (e&3)]
#pragma unroll
            for (int q = 0; q < 2; ++q) {
                bf16x8 bh_, bl_;
#pragma unroll
                for (int e = 0; e < 8; ++e) {
                    unsigned short hh, ll;
                    split2(p[(2 * q + (e >> 2)) * 4 + (e & 3)], hh, ll);
                    bh_[e] = (short)hh;
                    bl_[e] = (short)ll;
                }
                pbh[g][q] = bh_;
                pbl[g][q] = bl_;
            }
        }

        // ---- PV: oacc = mfma(A=V^T permuted, B=P^T) ----
#pragma unroll
        for (int q = 0; q < 2; ++q)
#pragma unroll
            for (int df = 0; df < 4; ++df) {
                const int va = (df * 16 + lr) * 128 + ((((q << 2) | kg) ^ (lr & 7)) << 4);
                const bf16x8 avh = *(const bf16x8*)((const char*)smem + 16384 + va);
                const bf16x8 avl = *(const bf16x8*)((const char*)smem + 24576 + va);
#pragma unroll
                for (int g = 0; g < 2; ++g) {
                    oacc[g][df] = __builtin_amdgcn_mfma_f32_16x16x32_bf16(avh, pbh[g][q], oacc[g][df], 0, 0, 0);
                    oacc[g][df] = __builtin_amdgcn_mfma_f32_16x16x32_bf16(avh, pbl[g][q], oacc[g][df], 0, 0, 0);
                    oacc[g][df] = __builtin_amdgcn_mfma_f32_16x16x32_bf16(avl, pbh[g][q], oacc[g][df], 0, 0, 0);
                }
            }

        __syncthreads();                 // all waves done reading V (K staged)
        if (it + 1 < NT) stageV(it + 1); // V(i+1) flies under next QK
    }

    // ---- epilogue: O^T -> global. row s, col d; lane-uniform lsum ----
#pragma unroll
    for (int g = 0; g < 2; ++g) {
        const float rinv = 1.f / lsum[g];
        const int srow = b * SEQ + s0 + w * 32 + g * 16 + lr;
#pragma unroll
        for (int df = 0; df < 4; ++df)
#pragma unroll
            for (int j = 0; j < 4; ++j) {
                const float v = oacc[g][df][j] * rinv;
                const int col = h * DH + df * 16 + kg * 4 + j;
                unsigned short hh, ll;
                split2(v, hh, ll);
                ah[(size_t)srow * 1024 + col] = hh;
                al[(size_t)srow * 1024 + col] = ll;
            }
    }
}

// ---------------------------------------------------------------------------
extern "C" void kernel_launch(void* const* d_in, const int* in_sizes, int n_in,
                              void* d_out, int out_size, void* d_ws, size_t ws_size,
                              hipStream_t stream)
{
    const float* x      = (const float*)d_in[0];
    const float* enc    = (const float*)d_in[1];
    const float* w_attn = (const float*)d_in[2];
    const float* b_attn = (const float*)d_in[3];
    const float* w_vis  = (const float*)d_in[4];
    const float* b_vis  = (const float*)d_in[5];
    const float* w_proj = (const float*)d_in[6];
    const float* b_proj = (const float*)d_in[7];
    float* out = (float*)d_out;

    // ---- workspace (total 65,011,712 B — identical to validated rounds) ----
    char* base = (char*)d_ws;
    unsigned short* xh   = (unsigned short*)(base + 0);          // 8 MiB
    unsigned short* xl   = (unsigned short*)(base + 8388608);    // 8 MiB
    unsigned short* ench = (unsigned short*)(base + 16777216);   // 4.5 MiB
    unsigned short* encl = (unsigned short*)(base + 21495808);
    unsigned short* w1h  = (unsigned short*)(base + 26214400);   // 2 MiB each
    unsigned short* w1l  = (unsigned short*)(base + 28311552);
    unsigned short* w2h  = (unsigned short*)(base + 30408704);
    unsigned short* w2l  = (unsigned short*)(base + 32505856);
    unsigned short* w3h  = (unsigned short*)(base + 34603008);
    unsigned short* w3l  = (unsigned short*)(base + 36700160);
    unsigned short* qh   = (unsigned short*)(base + 38797312);   // 8 MiB
    unsigned short* ql   = (unsigned short*)(base + 47185920);
    unsigned short* kvh  = (unsigned short*)(base + 55574528);   // 4.5 MiB
    unsigned short* kvl  = (unsigned short*)(base + 60293120);   // ends 65011712
    // phase aliases:
    unsigned short* vph  = (unsigned short*)(base + 0);          // over xh/xl (dead after gemm12)
    unsigned short* vpl  = (unsigned short*)(base + 4718592);
    unsigned short* atth = (unsigned short*)(base + 16777216);   // over ench/encl (dead after gemm12)
    unsigned short* attl = (unsigned short*)(base + 26214400);   // over w1/w2 (dead after gemm12)

    // ---- operand prep ----
    split_rm<<<(MQ  * 1024 / 4) / 256, 256, 0, stream>>>(x, xh, xl);
    split_rm<<<(MKV * 1024 / 4) / 256, 256, 0, stream>>>(enc, ench, encl);
    split_tr<<<dim3(32, 32), 256, 0, stream>>>(w_attn, 3 * D_MODEL, w1h, w1l); // q-slice
    split_tr<<<dim3(32, 32), 256, 0, stream>>>(w_vis,  D_MODEL, w2h, w2l);
    split_tr<<<dim3(32, 32), 256, 0, stream>>>(w_proj, D_MODEL, w3h, w3l);

    // ---- q = x@w1+b1 and kv = enc@w2+b2, merged (400 blocks, bf16 h/l out) ----
    gemm12_split_mfma<<<dim3(8, 50), 256, 0, stream>>>(
        xh, xl, w1h, w1l, b_attn, qh, ql,
        ench, encl, w2h, w2l, b_vis, kvh, kvl);
    // ---- V^T permuted per (b,h): [bh][64 d][9 tiles][64 slots] ----
    transpose_perm<<<dim3(NT, BATCH * NHEAD), 256, 0, stream>>>(kvh, kvl, vph, vpl);
    // ---- attention (MFMA, swapped-operand) -> bf16 hi/lo ----
    attn_mfma<<<dim3(SEQ / 128, BATCH * NHEAD), 256, 0, stream>>>(
        qh, ql, kvh, kvl, vph, vpl, atth, attl);
    // ---- out = att @ w_proj + b_proj (fp32) ----
    gemm_split_mfma_f32<<<dim3(8, MQ / 128), 256, 0, stream>>>(
        atth, attl, w3h, w3l, b_proj, out);
}